// Round 6
// baseline (230.179 us; speedup 1.0000x reference)
//
#include <hip/hip_runtime.h>
#include <hip/hip_bf16.h>
#include <stdint.h>

#define B_ROWS 16384   // batch rows (M)
#define C_ROWS 2048    // class rows (N)
#define D_FULL 512     // input feature dim
#define KP     512     // padded K (511 real + 1 zero col)

#define STRIPS  16     // N strips of 128
#define MSPLIT  16     // M splits of 1024 rows
#define CHUNK_M 64     // rows per chunk (A-chunk = 64 KB LDS)
#define NCHUNK  16     // chunks per block (16 x 64 = 1024 rows)

typedef __attribute__((ext_vector_type(8))) short bf16x8;
typedef __attribute__((ext_vector_type(4))) float f32x4;

typedef __attribute__((address_space(1))) void glb_void;
typedef __attribute__((address_space(3))) void lds_void;

// async global->LDS, 16B per lane; LDS dest = wave-uniform base + lane*16
__device__ __forceinline__ void gld16(const void* g, void* l) {
    __builtin_amdgcn_global_load_lds((glb_void*)(uintptr_t)g,
                                     (lds_void*)(uintptr_t)l, 16, 0, 0);
}

// ---------------------------------------------------------------------------
// Prep: per row, cast cols [1..511] -> bf16 (padded to 512 with trailing 0),
// and compute norm = sqrt(1 + sum(rest^2)) in fp32.
// ---------------------------------------------------------------------------
__global__ __launch_bounds__(256) void prep_kernel(
    const float* __restrict__ x, const float* __restrict__ pts,
    unsigned short* __restrict__ Abf, unsigned short* __restrict__ Bbf,
    float* __restrict__ xn, float* __restrict__ pn)
{
    int row = blockIdx.x;
    const float* src;
    unsigned short* dst;
    float* nrm;
    if (row < B_ROWS) {
        src = x + (size_t)row * D_FULL;
        dst = Abf + (size_t)row * KP;
        nrm = xn + row;
    } else {
        int r = row - B_ROWS;
        src = pts + (size_t)r * D_FULL;
        dst = Bbf + (size_t)r * KP;
        nrm = pn + r;
    }
    int t = threadIdx.x;
    float v0 = src[2 * t + 1];
    float v1 = (t < 255) ? src[2 * t + 2] : 0.0f;    // k==511 -> pad 0
    __hip_bfloat16 b0 = __float2bfloat16(v0);
    __hip_bfloat16 b1 = __float2bfloat16(v1);
    union { unsigned short u[2]; unsigned int w; } pack;
    pack.u[0] = *(unsigned short*)&b0;
    pack.u[1] = *(unsigned short*)&b1;
    *(unsigned int*)&dst[2 * t] = pack.w;
    float ss = v0 * v0 + v1 * v1;
    #pragma unroll
    for (int off = 32; off > 0; off >>= 1) ss += __shfl_down(ss, off);
    __shared__ float red[4];
    if ((t & 63) == 0) red[t >> 6] = ss;
    __syncthreads();
    if (t == 0) nrm[0] = sqrtf(1.0f + red[0] + red[1] + red[2] + red[3]);
}

// ---------------------------------------------------------------------------
// Persistent-block GEMM: grid = 256 = 1 block/CU. Block (s = bx>>4, m = bx&15)
// owns N-strip [s*128, s*128+128) and M-range [m*1024, m*1024+1024), walked as
// 16 chunks of 64 rows. A-chunk (64x512 bf16 = 64 KB) double-buffered in LDS
// via global_load_lds; B fragments loaded DIRECT global->register (per-k-step
// B slice = 8 KB -> L1-resident; whole strip = 128 KB -> L2-resident).
// ONE barrier per chunk = per 128 MFMA/wave (vs 1 per 32 in the m97 shape).
// Same-m blocks (stride 16 ≡ 0 mod 8) land on the same XCD -> each A chunk is
// fetched from HBM once, L2-shared by the 16 strips.
// LDS XOR swizzle (row stride 1024 B ≡ bank-aligned): 16B-chunk pos p of row r
// holds global chunk p ^ (r&7); staging rows r = 4i+wave have r&7 = wave or
// wave+4 -> two precomputed source-col patterns. Fragment reads 2-way (free).
// Epilogue per chunk: out = -arccosh(max(x0[m]*p0[n] - acc, 1+eps)).
// ---------------------------------------------------------------------------
__global__ __launch_bounds__(256, 1) void gemm_kernel(
    const unsigned short* __restrict__ A,   // [B_ROWS][KP] bf16
    const unsigned short* __restrict__ Bm,  // [C_ROWS][KP] bf16
    const float* __restrict__ xn, const float* __restrict__ pn,
    float* __restrict__ out)
{
    __shared__ unsigned short As[2][CHUNK_M * KP];   // 2 x 64 KB

    const int tid  = threadIdx.x;
    const int wave = tid >> 6;
    const int lane = tid & 63;
    const int wm   = wave >> 1;        // 0..1 : M-half of chunk (32 rows)
    const int wn   = wave & 1;         // 0..1 : N-half of strip (64 cols)
    const int lrow = lane & 15;
    const int quad = lane >> 4;        // 0..3

    const int m     = blockIdx.x & 15;             // M-split (same-m -> same XCD)
    const int s     = blockIdx.x >> 4;             // N-strip
    const int n0    = s * 128;
    const int mBase = m * (CHUNK_M * NCHUNK);      // m * 1024

    // B fragment base pointers: 4 n-tiles, K-major; k-step advance = immediate
    const unsigned short* bPtr[4];
    #pragma unroll
    for (int nt = 0; nt < 4; ++nt)
        bPtr[nt] = Bm + (size_t)(n0 + wn * 64 + nt * 16 + lrow) * KP + quad * 8;

    // staging source element-cols; rows r = 4i+wave  =>  r&7 = wave (+4 if i odd)
    const int colEven = (lane ^ wave) << 3;
    const int colOdd  = (lane ^ (wave + 4)) << 3;

    const unsigned short* gA = A + (size_t)(mBase)*KP;   // chunk row offset added per stage

    // fragment-read swizzle inputs
    const int sA = lrow & 7;

    float pv[4];
    #pragma unroll
    for (int nt = 0; nt < 4; ++nt)
        pv[nt] = pn[n0 + wn * 64 + nt * 16 + lrow];

    // prologue: stage chunk 0 -> buf 0
    #pragma unroll
    for (int i = 0; i < 16; ++i) {
        int r = i * 4 + wave;
        gld16(gA + (size_t)r * KP + ((i & 1) ? colOdd : colEven), &As[0][r * KP]);
    }

    for (int ch = 0; ch < NCHUNK; ++ch) {
        const int buf = ch & 1;
        __syncthreads();   // staging of chunk ch (into buf) complete; prev ds_reads done

        f32x4 acc[2][4] = {};
        #pragma unroll
        for (int ks = 0; ks < 16; ++ks) {
            bf16x8 af[2], bfr[4];
            #pragma unroll
            for (int mt = 0; mt < 2; ++mt) {
                int rl = wm * 32 + mt * 16 + lrow;
                int chunk = ((ks * 4 + quad) ^ sA);
                af[mt] = *(const bf16x8*)&As[buf][rl * KP + (chunk << 3)];
            }
            #pragma unroll
            for (int nt = 0; nt < 4; ++nt)
                bfr[nt] = *(const bf16x8*)(bPtr[nt] + ks * 32);
            #pragma unroll
            for (int mt = 0; mt < 2; ++mt)
                #pragma unroll
                for (int nt = 0; nt < 4; ++nt)
                    acc[mt][nt] = __builtin_amdgcn_mfma_f32_16x16x32_bf16(
                        af[mt], bfr[nt], acc[mt][nt], 0, 0, 0);
        }

        // stage next chunk AFTER all B-loads (vmcnt FIFO: B-uses never wait on it)
        if (ch + 1 < NCHUNK) {
            const unsigned short* gAn = gA + (size_t)(ch + 1) * CHUNK_M * KP;
            #pragma unroll
            for (int i = 0; i < 16; ++i) {
                int r = i * 4 + wave;
                gld16(gAn + (size_t)r * KP + ((i & 1) ? colOdd : colEven),
                      &As[buf ^ 1][r * KP]);
            }
        }

        // epilogue for chunk ch: C/D layout col = lane&15, row = quad*4 + reg
        #pragma unroll
        for (int mt = 0; mt < 2; ++mt) {
            #pragma unroll
            for (int r = 0; r < 4; ++r) {
                int row = mBase + ch * CHUNK_M + wm * 32 + mt * 16 + quad * 4 + r;
                float xv = xn[row];
                size_t base = (size_t)row * C_ROWS + n0 + wn * 64 + lrow;
                #pragma unroll
                for (int nt = 0; nt < 4; ++nt) {
                    float z = fmaf(xv, pv[nt], -acc[mt][nt][r]);
                    z = fmaxf(z, 1.0f + 1e-7f);
                    // arccosh(z) = log(z + sqrt(z^2-1)); z >= ~20, no cancellation
                    out[base + nt * 16] = -__logf(z + __fsqrt_rn(z * z - 1.0f));
                }
            }
        }
    }
}

extern "C" void kernel_launch(void* const* d_in, const int* in_sizes, int n_in,
                              void* d_out, int out_size, void* d_ws, size_t ws_size,
                              hipStream_t stream) {
    const float* x   = (const float*)d_in[0];
    const float* pts = (const float*)d_in[1];
    float* out = (float*)d_out;

    char* ws = (char*)d_ws;
    unsigned short* Abf = (unsigned short*)ws;                                 // 16 MB
    unsigned short* Bbf = (unsigned short*)(ws + (size_t)B_ROWS * KP * 2);     // 2 MB
    float* xn = (float*)(ws + (size_t)(B_ROWS + C_ROWS) * KP * 2);             // 64 KB
    float* pn = (float*)((char*)xn + (size_t)B_ROWS * 4);                      // 8 KB
    (void)in_sizes; (void)n_in; (void)out_size; (void)ws_size;

    prep_kernel<<<B_ROWS + C_ROWS, 256, 0, stream>>>(x, pts, Abf, Bbf, xn, pn);

    gemm_kernel<<<STRIPS * MSPLIT, 256, 0, stream>>>(Abf, Bbf, xn, pn, out);
}

// Round 7
// 228.103 us; speedup vs baseline: 1.0091x; 1.0091x over previous
//
#include <hip/hip_runtime.h>
#include <hip/hip_bf16.h>
#include <stdint.h>

#define B_ROWS 16384   // batch rows (M)
#define C_ROWS 2048    // class rows (N)
#define D_FULL 512     // input feature dim
#define KP     512     // padded K (511 real + 1 zero col)

#define BM 128
#define BN 128
#define BK 64          // 8 K-iters

typedef __attribute__((ext_vector_type(8))) short bf16x8;
typedef __attribute__((ext_vector_type(4))) float f32x4;

typedef __attribute__((address_space(1))) void glb_void;
typedef __attribute__((address_space(3))) void lds_void;

// async global->LDS, 16B per lane; LDS dest = wave-uniform base + lane*16
__device__ __forceinline__ void gld16(const void* g, void* l) {
    __builtin_amdgcn_global_load_lds((glb_void*)(uintptr_t)g,
                                     (lds_void*)(uintptr_t)l, 16, 0, 0);
}

// ---------------------------------------------------------------------------
// Prep: per row, cast cols [1..511] -> bf16 (padded to 512 with trailing 0),
// and compute norm = sqrt(1 + sum(rest^2)) in fp32.
// ---------------------------------------------------------------------------
__global__ __launch_bounds__(256) void prep_kernel(
    const float* __restrict__ x, const float* __restrict__ pts,
    unsigned short* __restrict__ Abf, unsigned short* __restrict__ Bbf,
    float* __restrict__ xn, float* __restrict__ pn)
{
    int row = blockIdx.x;
    const float* src;
    unsigned short* dst;
    float* nrm;
    if (row < B_ROWS) {
        src = x + (size_t)row * D_FULL;
        dst = Abf + (size_t)row * KP;
        nrm = xn + row;
    } else {
        int r = row - B_ROWS;
        src = pts + (size_t)r * D_FULL;
        dst = Bbf + (size_t)r * KP;
        nrm = pn + r;
    }
    int t = threadIdx.x;
    float v0 = src[2 * t + 1];
    float v1 = (t < 255) ? src[2 * t + 2] : 0.0f;    // k==511 -> pad 0
    __hip_bfloat16 b0 = __float2bfloat16(v0);
    __hip_bfloat16 b1 = __float2bfloat16(v1);
    union { unsigned short u[2]; unsigned int w; } pack;
    pack.u[0] = *(unsigned short*)&b0;
    pack.u[1] = *(unsigned short*)&b1;
    *(unsigned int*)&dst[2 * t] = pack.w;
    float ss = v0 * v0 + v1 * v1;
    #pragma unroll
    for (int off = 32; off > 0; off >>= 1) ss += __shfl_down(ss, off);
    __shared__ float red[4];
    if ((t & 63) == 0) red[t >> 6] = ss;
    __syncthreads();
    if (t == 0) nrm[0] = sqrtf(1.0f + red[0] + red[1] + red[2] + red[3]);
}

// ---------------------------------------------------------------------------
// GEMM: C[m][n] = sum_k A[m][k]*B[n][k], both K-major. 128x128 tile, 4 waves
// 2x2, wave 64x64 via 4x4 of 16x16x32 bf16.
// A: LDS, double-buffered 2 x 16 KB, R2's VERIFIED XOR swizzle (16B-chunk pos
//    p of row r holds global chunk p ^ (r&7)); 1 barrier/iter; the vmcnt(0)
//    drain at each barrier covers A-staging issued a full compute phase ago.
// B: DIRECT global->register (2 MB, L2-resident — R3/R6 showed B direct
//    fetches cheaply), prefetched one iter ahead mid-compute; B-loads never
//    couple to the barrier, giving cross-barrier in-flight vmem (AITER-style).
// Epilogue: out = -arccosh(max(x0[m]*p0[n] - acc, 1+eps))
// ---------------------------------------------------------------------------
__global__ __launch_bounds__(256) void gemm_kernel(
    const unsigned short* __restrict__ A,   // [B_ROWS][KP] bf16
    const unsigned short* __restrict__ Bm,  // [C_ROWS][KP] bf16
    const float* __restrict__ xn, const float* __restrict__ pn,
    float* __restrict__ out)
{
    __shared__ unsigned short As[2][BM * BK];   // 2 x 16 KB

    const int tid  = threadIdx.x;
    const int wave = tid >> 6;
    const int lane = tid & 63;
    const int wm   = wave >> 1;        // 0..1
    const int wn   = wave & 1;         // 0..1
    const int lrow = lane & 15;
    const int quad = lane >> 4;        // 0..3

    const int bm0 = blockIdx.x * BM;
    const int bn0 = blockIdx.y * BN;

    // A staging (R2 verified): wave covers 32 rows/tile in 4 issues of 8 rows;
    // lane's LDS chunk pos = lane&7, row-within-8 = lane>>3; global source
    // chunk = (lane&7) ^ (row&7). (+8i preserves row&7.)
    const int srow = wave * 32 + (lane >> 3);
    const int scol = (((lane & 7) ^ ((lane >> 3) & 7)) << 3);
    const unsigned short* gA = A + (size_t)(bm0 + srow) * KP + scol;

    // B fragment pointers: 4 n-tiles, K-major; k advance via immediate offsets
    const unsigned short* bPtr[4];
    #pragma unroll
    for (int nt = 0; nt < 4; ++nt)
        bPtr[nt] = Bm + (size_t)(bn0 + wn * 64 + nt * 16 + lrow) * KP + quad * 8;

    f32x4 acc[4][4] = {};

    // prologue: stage A k-block 0 into buf 0; load B k-block 0 into regs
    #pragma unroll
    for (int i = 0; i < 4; ++i)
        gld16(gA + (size_t)(i * 8) * KP, &As[0][(wave * 32 + i * 8) * BK]);

    bf16x8 bcur[2][4], bnxt[2][4];
    #pragma unroll
    for (int h = 0; h < 2; ++h)
        #pragma unroll
        for (int nt = 0; nt < 4; ++nt)
            bcur[h][nt] = *(const bf16x8*)(bPtr[nt] + h * 32);

    for (int it = 0; it < KP / BK; ++it) {
        const int buf = it & 1;
        const int k1 = (it + 1) * BK;
        __syncthreads();   // A-staging of buf (issued a full compute phase ago) done
        if (it + 1 < KP / BK) {
            // stage next A tile into other buffer (drained at NEXT barrier)
            #pragma unroll
            for (int i = 0; i < 4; ++i)
                gld16(gA + (size_t)(i * 8) * KP + k1,
                      &As[buf ^ 1][(wave * 32 + i * 8) * BK]);
            // prefetch next B k-block into registers (never barrier-coupled)
            #pragma unroll
            for (int h = 0; h < 2; ++h)
                #pragma unroll
                for (int nt = 0; nt < 4; ++nt)
                    bnxt[h][nt] = *(const bf16x8*)(bPtr[nt] + k1 + h * 32);
        }
        #pragma unroll
        for (int kk = 0; kk < BK; kk += 32) {
            const int ch0 = kk >> 3;             // chunk base: 0 or 4
            bf16x8 af[4];
            #pragma unroll
            for (int mi = 0; mi < 4; ++mi) {
                int r = wm * 64 + mi * 16 + lrow;
                af[mi] = *(const bf16x8*)&As[buf][r * BK + (((ch0 + quad) ^ (lrow & 7)) << 3)];
            }
            #pragma unroll
            for (int mi = 0; mi < 4; ++mi)
                #pragma unroll
                for (int ni = 0; ni < 4; ++ni)
                    acc[mi][ni] = __builtin_amdgcn_mfma_f32_16x16x32_bf16(
                        af[mi], bcur[kk >> 5][ni], acc[mi][ni], 0, 0, 0);
        }
        #pragma unroll
        for (int h = 0; h < 2; ++h)
            #pragma unroll
            for (int nt = 0; nt < 4; ++nt)
                bcur[h][nt] = bnxt[h][nt];
    }

    // epilogue: C/D layout col = lane&15, row = quad*4 + reg
    float pv[4];
    #pragma unroll
    for (int ni = 0; ni < 4; ++ni)
        pv[ni] = pn[bn0 + wn * 64 + ni * 16 + lrow];

    #pragma unroll
    for (int mi = 0; mi < 4; ++mi) {
        #pragma unroll
        for (int r = 0; r < 4; ++r) {
            int row = bm0 + wm * 64 + mi * 16 + quad * 4 + r;
            float xv = xn[row];
            size_t base = (size_t)row * C_ROWS + bn0 + wn * 64 + lrow;
            #pragma unroll
            for (int ni = 0; ni < 4; ++ni) {
                float z = fmaf(xv, pv[ni], -acc[mi][ni][r]);
                z = fmaxf(z, 1.0f + 1e-7f);
                // arccosh(z) = log(z + sqrt(z^2-1)); z >= ~20, no cancellation
                out[base + ni * 16] = -__logf(z + __fsqrt_rn(z * z - 1.0f));
            }
        }
    }
}

extern "C" void kernel_launch(void* const* d_in, const int* in_sizes, int n_in,
                              void* d_out, int out_size, void* d_ws, size_t ws_size,
                              hipStream_t stream) {
    const float* x   = (const float*)d_in[0];
    const float* pts = (const float*)d_in[1];
    float* out = (float*)d_out;

    char* ws = (char*)d_ws;
    unsigned short* Abf = (unsigned short*)ws;                                 // 16 MB
    unsigned short* Bbf = (unsigned short*)(ws + (size_t)B_ROWS * KP * 2);     // 2 MB
    float* xn = (float*)(ws + (size_t)(B_ROWS + C_ROWS) * KP * 2);             // 64 KB
    float* pn = (float*)((char*)xn + (size_t)B_ROWS * 4);                      // 8 KB
    (void)in_sizes; (void)n_in; (void)out_size; (void)ws_size;

    prep_kernel<<<B_ROWS + C_ROWS, 256, 0, stream>>>(x, pts, Abf, Bbf, xn, pn);

    dim3 grid(B_ROWS / BM, C_ROWS / BN);
    gemm_kernel<<<grid, 256, 0, stream>>>(Abf, Bbf, xn, pn, out);
}